// Round 11
// baseline (423.749 us; speedup 1.0000x reference)
//
#include <hip/hip_runtime.h>
#include <cstdint>
#include <cstddef>

#define DIM 16384
#define BSIZE 32
#define MAX_STEPS 9
#define TPB1 256
#define TPB3 1024
#define JB 512
#define NSLOTS (DIM / JB)  // 32
#define BATCH 8

typedef float f32x4 __attribute__((ext_vector_type(4)));

__device__ __forceinline__ float rdlane(float v, int l) {
    return __int_as_float(__builtin_amdgcn_readlane(__float_as_int(v), l));
}

// ---------------- K0: tiled transpose x [B][D] -> xT [D][B] ----------------
__global__ __launch_bounds__(256) void k_xpose(const float* __restrict__ x,
                                               float* __restrict__ xT) {
    __shared__ float tile[64][33];
    const int j0 = blockIdx.x * 64;
    const int t = threadIdx.x;
    {
        int col = t & 63;
        int r0 = t >> 6;  // 0..3
#pragma unroll
        for (int r = 0; r < 8; ++r) {
            int row = r * 4 + r0;  // 0..31
            tile[col][row] = x[(size_t)row * DIM + j0 + col];
        }
    }
    __syncthreads();
    {
        int b = t & 31;
        int q0 = t >> 5;  // 0..7
#pragma unroll
        for (int r = 0; r < 8; ++r) {
            int jj = r * 8 + q0;  // 0..63
            xT[(size_t)(j0 + jj) * BSIZE + b] = tile[jj][b];
        }
    }
}

// ------- K1: partial[slot][b][c] = sum_{j in slot} x[b][j] * W[j][c] -------
// R9 probe-mirror structure + depth-2 ping-pong: two register sets (8 W rows
// f32x4 + one x f32x4 each). Loads for batch g+2 are issued right after
// computing batch g, so each 1536-cyc compute phase covers the next batch's
// memory latency (~18 loads/wave in flight, ~32KB/CU outstanding). x values
// extracted with compile-time v_readlane, feeding v_pk_fma_f32.
// grid (16, 32) = 512 blocks = 2/CU = 8 waves/CU.
__global__ __launch_bounds__(TPB1, 2) void k_matmul(
        const float* __restrict__ W, const float* __restrict__ xT,
        float* __restrict__ partial) {
    const int t = threadIdx.x;
    const int l = t & 63;
    const int c0 = (blockIdx.x * TPB1 + t) * 4;
    const int j0 = blockIdx.y * JB;

    f32x4 acc[BSIZE];
#pragma unroll
    for (int b = 0; b < BSIZE; ++b) acc[b] = (f32x4)(0.f);

    const float* wp = W + (size_t)j0 * DIM + c0;
    const float* xp = xT + (size_t)j0 * BSIZE + l * 4;

    f32x4 vA[BATCH], vB[BATCH], xA, xB;

    // prologue: batch 0 -> A, batch 1 -> B (x issued before the W rows)
    xA = *(const f32x4*)xp;
#pragma unroll
    for (int r = 0; r < BATCH; ++r)
        vA[r] = *(const f32x4*)(wp + (size_t)r * DIM);
    xB = *(const f32x4*)(xp + 256);
#pragma unroll
    for (int r = 0; r < BATCH; ++r)
        vB[r] = *(const f32x4*)(wp + (size_t)(BATCH + r) * DIM);

    const int NG = JB / BATCH;  // 64 (even -> no tail on the +=2 loop)
    for (int g = 0; g < NG; g += 2) {
        // ---- compute batch g from A ----
        // x float for (row r, batch b): lane r*8+(b>>2), elem b&3 (compile-time)
#pragma unroll
        for (int r = 0; r < BATCH; ++r) {
            f32x4 w4 = vA[r];
#pragma unroll
            for (int b = 0; b < BSIZE; ++b) {
                float xs = rdlane(xA[b & 3], r * 8 + (b >> 2));
                acc[b] = __builtin_elementwise_fma(w4, (f32x4)(xs), acc[b]);
            }
        }
        // ---- issue batch g+2 -> A (clamped at tail; duplicate loads harmless) ----
        {
            int gn = (g + 2 < NG) ? (g + 2) : (NG - 1);
            xA = *(const f32x4*)(xp + (size_t)gn * 256);
            const float* wr = wp + (size_t)gn * BATCH * DIM;
#pragma unroll
            for (int r = 0; r < BATCH; ++r)
                vA[r] = *(const f32x4*)(wr + (size_t)r * DIM);
        }
        // ---- compute batch g+1 from B ----
#pragma unroll
        for (int r = 0; r < BATCH; ++r) {
            f32x4 w4 = vB[r];
#pragma unroll
            for (int b = 0; b < BSIZE; ++b) {
                float xs = rdlane(xB[b & 3], r * 8 + (b >> 2));
                acc[b] = __builtin_elementwise_fma(w4, (f32x4)(xs), acc[b]);
            }
        }
        // ---- issue batch g+3 -> B ----
        {
            int gn = (g + 3 < NG) ? (g + 3) : (NG - 1);
            xB = *(const f32x4*)(xp + (size_t)gn * 256);
            const float* wr = wp + (size_t)gn * BATCH * DIM;
#pragma unroll
            for (int r = 0; r < BATCH; ++r)
                vB[r] = *(const f32x4*)(wr + (size_t)r * DIM);
        }
    }

    float* pbase = partial + (size_t)blockIdx.y * BSIZE * DIM + c0;
#pragma unroll
    for (int b = 0; b < BSIZE; ++b)
        *(f32x4*)(pbase + (size_t)b * DIM) = acc[b];
}

// ------- K2: h0 = sum_slots partial + bias (float4, deterministic order) -------
__global__ __launch_bounds__(256) void k_reduce(const float* __restrict__ partial,
                                                const float* __restrict__ bias,
                                                float* __restrict__ h0) {
    int i4 = blockIdx.x * 256 + threadIdx.x;  // over B*DIM/4
    int c4 = i4 & (DIM / 4 - 1);
    const f32x4* p = (const f32x4*)partial;
    f32x4 s = ((const f32x4*)bias)[c4];
#pragma unroll 4
    for (int sl = 0; sl < NSLOTS; ++sl)
        s += p[(size_t)sl * (BSIZE * DIM / 4) + i4];
    ((f32x4*)h0)[i4] = s;
}

// ---------------- K3 block-wide reductions (1024 thr = 16 waves) ----------------
__device__ __forceinline__ float block_reduce_max(float v, float* red) {
#pragma unroll
    for (int off = 1; off < 64; off <<= 1) v = fmaxf(v, __shfl_xor(v, off));
    int lane = threadIdx.x & 63, wv = threadIdx.x >> 6;
    if (lane == 0) red[wv] = v;
    __syncthreads();
    float m = red[0];
#pragma unroll
    for (int w = 1; w < TPB3 / 64; ++w) m = fmaxf(m, red[w]);
    __syncthreads();  // allow red[] reuse
    return m;
}

__device__ __forceinline__ float block_reduce_sum(float v, float* red) {
#pragma unroll
    for (int off = 1; off < 64; off <<= 1) v += __shfl_xor(v, off);
    int lane = threadIdx.x & 63, wv = threadIdx.x >> 6;
    if (lane == 0) red[wv] = v;
    __syncthreads();
    float s = red[0];
#pragma unroll
    for (int w = 1; w < TPB3 / 64; ++w) s += red[w];
    __syncthreads();
    return s;
}

// ------- K3: per-row sampler, one block per batch row, h/sg in registers -------
__global__ __launch_bounds__(TPB3) void k_sample(
        const float* __restrict__ x, const float* __restrict__ W,
        const float* __restrict__ h0, const float* __restrict__ gumbel,
        const float* __restrict__ au, const int* __restrict__ radius,
        float* __restrict__ out) {
    __shared__ float redf[TPB3 / 64];
    __shared__ int   redi[TPB3 / 64];
    __shared__ float s_delta;
    const int b = blockIdx.x;
    const int t = threadIdx.x;
    const int lane = t & 63, wvi = t >> 6;

    const f32x4* h0v = (const f32x4*)(h0 + (size_t)b * DIM);
    const f32x4* xin = (const f32x4*)(x + (size_t)b * DIM);

    f32x4 h[4], sg[4];
#pragma unroll
    for (int v = 0; v < 4; ++v) {
        h[v] = h0v[t + v * TPB3];
        f32x4 xx = xin[t + v * TPB3];
        sg[v] = (f32x4)(1.0f) - 2.0f * xx;  // exactly +/-1
    }

    // Zx = logsumexp(sg*h*0.5)
    float lmax = -INFINITY;
#pragma unroll
    for (int v = 0; v < 4; ++v) {
        f32x4 l = sg[v] * h[v] * 0.5f;
        lmax = fmaxf(lmax, fmaxf(fmaxf(l.x, l.y), fmaxf(l.z, l.w)));
    }
    float m = block_reduce_max(lmax, redf);
    float lsum = 0.f;
#pragma unroll
    for (int v = 0; v < 4; ++v) {
        f32x4 l = sg[v] * h[v] * 0.5f;
        lsum += expf(l.x - m) + expf(l.y - m) + expf(l.z - m) + expf(l.w - m);
    }
    float S = block_reduce_sum(lsum, redf);
    float Zx = logf(S) + m;

    int rad = radius[b];
    rad = rad < 0 ? 0 : (rad > MAX_STEPS ? MAX_STEPS : rad);

    f32x4 gc[4];
    {
        const f32x4* gp = (const f32x4*)(gumbel + (size_t)b * DIM);  // step 0 row
#pragma unroll
        for (int v = 0; v < 4; ++v) gc[v] = gp[t + v * TPB3];
    }

    for (int st = 0; st < rad; ++st) {
        // scores + thread-local argmax (ascending index; strict > keeps first max)
        float best = -INFINITY; int bidx = 0;
#pragma unroll
        for (int v = 0; v < 4; ++v) {
            f32x4 l = sg[v] * h[v] * 0.5f + gc[v];
            int base = (t + v * TPB3) * 4;
            if (l.x > best) { best = l.x; bidx = base; }
            if (l.y > best) { best = l.y; bidx = base + 1; }
            if (l.z > best) { best = l.z; bidx = base + 2; }
            if (l.w > best) { best = l.w; bidx = base + 3; }
        }
        // wave reduce (min-idx tie-break)
#pragma unroll
        for (int off = 1; off < 64; off <<= 1) {
            float ov = __shfl_xor(best, off);
            int oi = __shfl_xor(bidx, off);
            if (ov > best || (ov == best && oi < bidx)) { best = ov; bidx = oi; }
        }
        if (lane == 0) { redf[wvi] = best; redi[wvi] = bidx; }
        // prefetch next gumbel row; overlaps both barriers
        if (st + 1 < rad) {
            const f32x4* gp = (const f32x4*)(gumbel + ((size_t)(st + 1) * BSIZE + b) * DIM);
#pragma unroll
            for (int v = 0; v < 4; ++v) gc[v] = gp[t + v * TPB3];
        }
        __syncthreads();  // bar1: leader entries visible
        // all threads scan the 16 leader entries (identical result)
        float bv = redf[0]; int bi = redi[0];
#pragma unroll
        for (int w = 1; w < TPB3 / 64; ++w) {
            float ov = redf[w]; int oi = redi[w];
            if (ov > bv || (ov == bv && oi < bi)) { bv = ov; bi = oi; }
        }
        const int idx = bi;
        // issue W-row loads now; latency overlaps bar2
        const f32x4* wr4 = (const f32x4*)(W + (size_t)idx * DIM);
        f32x4 wl0 = wr4[t];
        f32x4 wl1 = wr4[t + TPB3];
        f32x4 wl2 = wr4[t + 2 * TPB3];
        f32x4 wl3 = wr4[t + 3 * TPB3];
        // owner flips its sign and publishes delta = (1 - 2*x_old)
        int c4 = idx >> 2, towner = c4 & (TPB3 - 1), vsel = c4 >> 10, e = idx & 3;
        if (t == towner) {
            f32x4 s4;
            if (vsel == 0) s4 = sg[0]; else if (vsel == 1) s4 = sg[1];
            else if (vsel == 2) s4 = sg[2]; else s4 = sg[3];
            float d = (e == 0) ? s4.x : (e == 1) ? s4.y : (e == 2) ? s4.z : s4.w;
            if (e == 0) s4.x = -s4.x; else if (e == 1) s4.y = -s4.y;
            else if (e == 2) s4.z = -s4.z; else s4.w = -s4.w;
            if (vsel == 0) sg[0] = s4; else if (vsel == 1) sg[1] = s4;
            else if (vsel == 2) sg[2] = s4; else sg[3] = s4;
            s_delta = d;
        }
        __syncthreads();  // bar2: s_delta visible; also protects redf/redi reuse
        float delta = s_delta;
        h[0].x = fmaf(delta, wl0.x, h[0].x); h[0].y = fmaf(delta, wl0.y, h[0].y);
        h[0].z = fmaf(delta, wl0.z, h[0].z); h[0].w = fmaf(delta, wl0.w, h[0].w);
        h[1].x = fmaf(delta, wl1.x, h[1].x); h[1].y = fmaf(delta, wl1.y, h[1].y);
        h[1].z = fmaf(delta, wl1.z, h[1].z); h[1].w = fmaf(delta, wl1.w, h[1].w);
        h[2].x = fmaf(delta, wl2.x, h[2].x); h[2].y = fmaf(delta, wl2.y, h[2].y);
        h[2].z = fmaf(delta, wl2.z, h[2].z); h[2].w = fmaf(delta, wl2.w, h[2].w);
        h[3].x = fmaf(delta, wl3.x, h[3].x); h[3].y = fmaf(delta, wl3.y, h[3].y);
        h[3].z = fmaf(delta, wl3.z, h[3].z); h[3].w = fmaf(delta, wl3.w, h[3].w);
    }

    // Zy
    lmax = -INFINITY;
#pragma unroll
    for (int v = 0; v < 4; ++v) {
        f32x4 l = sg[v] * h[v] * 0.5f;
        lmax = fmaxf(lmax, fmaxf(fmaxf(l.x, l.y), fmaxf(l.z, l.w)));
    }
    m = block_reduce_max(lmax, redf);
    lsum = 0.f;
#pragma unroll
    for (int v = 0; v < 4; ++v) {
        f32x4 l = sg[v] * h[v] * 0.5f;
        lsum += expf(l.x - m) + expf(l.y - m) + expf(l.z - m) + expf(l.w - m);
    }
    S = block_reduce_sum(lsum, redf);
    float Zy = logf(S) + m;

    int accepted = (expf(Zx - Zy) >= au[b]) ? 1 : 0;
    f32x4* ov = (f32x4*)(out + (size_t)b * DIM);
#pragma unroll
    for (int v = 0; v < 4; ++v) {
        f32x4 y;
        y.x = (sg[v].x < 0.f) ? 1.f : 0.f;
        y.y = (sg[v].y < 0.f) ? 1.f : 0.f;
        y.z = (sg[v].z < 0.f) ? 1.f : 0.f;
        y.w = (sg[v].w < 0.f) ? 1.f : 0.f;
        ov[t + v * TPB3] = accepted ? y : xin[t + v * TPB3];
    }
}

extern "C" void kernel_launch(void* const* d_in, const int* in_sizes, int n_in,
                              void* d_out, int out_size, void* d_ws, size_t ws_size,
                              hipStream_t stream) {
    (void)in_sizes; (void)n_in; (void)out_size; (void)ws_size;
    const float* x      = (const float*)d_in[0];
    const float* W      = (const float*)d_in[1];
    const float* bias   = (const float*)d_in[2];
    const float* gumbel = (const float*)d_in[3];
    const float* au     = (const float*)d_in[4];
    const int*   radius = (const int*)d_in[5];
    float* out = (float*)d_out;

    // ws layout: xT (2 MB) | partial (NSLOTS * 2 MB = 64 MB) | h0 (2 MB)
    float* xT = (float*)d_ws;
    size_t xt_elems = (size_t)DIM * BSIZE;
    float* partial = xT + xt_elems;
    float* h0 = partial + (size_t)NSLOTS * BSIZE * DIM;

    k_xpose<<<DIM / 64, 256, 0, stream>>>(x, xT);
    dim3 g1(DIM / (TPB1 * 4), NSLOTS);  // (16, 32) = 512 blocks
    k_matmul<<<g1, TPB1, 0, stream>>>(W, xT, partial);
    k_reduce<<<(BSIZE * DIM / 4) / 256, 256, 0, stream>>>(partial, bias, h0);
    k_sample<<<BSIZE, TPB3, 0, stream>>>(x, W, h0, gumbel, au, radius, out);
}

// Round 12
// 330.206 us; speedup vs baseline: 1.2833x; 1.2833x over previous
//
#include <hip/hip_runtime.h>
#include <cstdint>
#include <cstddef>

#define DIM 16384
#define BSIZE 32
#define MAX_STEPS 9
#define TPB1 256
#define TPB3 1024
#define JB 512
#define NSLOTS (DIM / JB)  // 32
#define BATCH 16

typedef float f32x2 __attribute__((ext_vector_type(2)));
typedef float f32x4 __attribute__((ext_vector_type(4)));

__device__ __forceinline__ float rdlane(float v, int l) {
    return __int_as_float(__builtin_amdgcn_readlane(__float_as_int(v), l));
}

// ---------------- K0: tiled transpose x [B][D] -> xT [D][B] ----------------
__global__ __launch_bounds__(256) void k_xpose(const float* __restrict__ x,
                                               float* __restrict__ xT) {
    __shared__ float tile[64][33];
    const int j0 = blockIdx.x * 64;
    const int t = threadIdx.x;
    {
        int col = t & 63;
        int r0 = t >> 6;  // 0..3
#pragma unroll
        for (int r = 0; r < 8; ++r) {
            int row = r * 4 + r0;  // 0..31
            tile[col][row] = x[(size_t)row * DIM + j0 + col];
        }
    }
    __syncthreads();
    {
        int b = t & 31;
        int q0 = t >> 5;  // 0..7
#pragma unroll
        for (int r = 0; r < 8; ++r) {
            int jj = r * 8 + q0;  // 0..63
            xT[(size_t)(j0 + jj) * BSIZE + b] = tile[jj][b];
        }
    }
}

// ------- K1: partial[slot][b][c] = sum_{j in slot} x[b][j] * W[j][c] -------
// R9's probe-validated batch-16 load shape at HIGH OCCUPANCY: 2 cols/thread
// (f32x2), acc = 64 VGPR, total ~115 VGPR -> 4 waves/SIMD, 16 waves/CU.
// The ~30% exposed batch-boundary latency of R9 (2 waves/SIMD) is now
// covered by cross-wave TLP instead of in-wave pipelining (which blew the
// register budget in R10). x rides ahead of each W batch as 2 f32x4/lane;
// compile-time v_readlane extracts feed v_pk_fma_f32 (1 per acc element).
// grid (32, 32) = 1024 blocks = 4/CU.
__global__ __launch_bounds__(TPB1, 4) void k_matmul(
        const float* __restrict__ W, const float* __restrict__ xT,
        float* __restrict__ partial) {
    const int t = threadIdx.x;
    const int l = t & 63;
    const int c0 = (blockIdx.x * TPB1 + t) * 2;
    const int j0 = blockIdx.y * JB;

    f32x2 acc[BSIZE];
#pragma unroll
    for (int b = 0; b < BSIZE; ++b) acc[b] = (f32x2)(0.f);

    const float* wp = W + (size_t)j0 * DIM + c0;
    const float* xp = xT + (size_t)j0 * BSIZE;

    for (int g = 0; g < JB / BATCH; ++g) {  // 32 batches
        // x for rows g*16..g*16+15 (512 floats): lane l holds 8, issued first
        f32x4 xv0 = *(const f32x4*)(xp + (size_t)g * 512 + l * 4);
        f32x4 xv1 = *(const f32x4*)(xp + (size_t)g * 512 + 256 + l * 4);
        // W batch: 16 rows back-to-back (probe shape), f32x2 per lane
        f32x2 v[BATCH];
#pragma unroll
        for (int r = 0; r < BATCH; ++r)
            v[r] = *(const f32x2*)(wp + (size_t)(g * BATCH + r) * DIM);
        // x float for (row r, batch b): reg r>>3, lane (r&7)*8+(b>>2), elem b&3
#pragma unroll
        for (int r = 0; r < BATCH; ++r) {
            f32x2 w2 = v[r];
#pragma unroll
            for (int b = 0; b < BSIZE; ++b) {
                float xs = (r < 8) ? rdlane(xv0[b & 3], (r & 7) * 8 + (b >> 2))
                                   : rdlane(xv1[b & 3], (r & 7) * 8 + (b >> 2));
                acc[b] = __builtin_elementwise_fma(w2, (f32x2)(xs), acc[b]);
            }
        }
    }

    float* pbase = partial + (size_t)blockIdx.y * BSIZE * DIM + c0;
#pragma unroll
    for (int b = 0; b < BSIZE; ++b)
        *(f32x2*)(pbase + (size_t)b * DIM) = acc[b];
}

// ------- K2: h0 = sum_slots partial + bias (float4, deterministic order) -------
__global__ __launch_bounds__(256) void k_reduce(const float* __restrict__ partial,
                                                const float* __restrict__ bias,
                                                float* __restrict__ h0) {
    int i4 = blockIdx.x * 256 + threadIdx.x;  // over B*DIM/4
    int c4 = i4 & (DIM / 4 - 1);
    const f32x4* p = (const f32x4*)partial;
    f32x4 s = ((const f32x4*)bias)[c4];
#pragma unroll 4
    for (int sl = 0; sl < NSLOTS; ++sl)
        s += p[(size_t)sl * (BSIZE * DIM / 4) + i4];
    ((f32x4*)h0)[i4] = s;
}

// ---------------- K3 block-wide reductions (1024 thr = 16 waves) ----------------
__device__ __forceinline__ float block_reduce_max(float v, float* red) {
#pragma unroll
    for (int off = 1; off < 64; off <<= 1) v = fmaxf(v, __shfl_xor(v, off));
    int lane = threadIdx.x & 63, wv = threadIdx.x >> 6;
    if (lane == 0) red[wv] = v;
    __syncthreads();
    float m = red[0];
#pragma unroll
    for (int w = 1; w < TPB3 / 64; ++w) m = fmaxf(m, red[w]);
    __syncthreads();  // allow red[] reuse
    return m;
}

__device__ __forceinline__ float block_reduce_sum(float v, float* red) {
#pragma unroll
    for (int off = 1; off < 64; off <<= 1) v += __shfl_xor(v, off);
    int lane = threadIdx.x & 63, wv = threadIdx.x >> 6;
    if (lane == 0) red[wv] = v;
    __syncthreads();
    float s = red[0];
#pragma unroll
    for (int w = 1; w < TPB3 / 64; ++w) s += red[w];
    __syncthreads();
    return s;
}

// ------- K3: per-row sampler, one block per batch row, h/sg in registers -------
__global__ __launch_bounds__(TPB3) void k_sample(
        const float* __restrict__ x, const float* __restrict__ W,
        const float* __restrict__ h0, const float* __restrict__ gumbel,
        const float* __restrict__ au, const int* __restrict__ radius,
        float* __restrict__ out) {
    __shared__ float redf[TPB3 / 64];
    __shared__ int   redi[TPB3 / 64];
    __shared__ float s_delta;
    const int b = blockIdx.x;
    const int t = threadIdx.x;
    const int lane = t & 63, wvi = t >> 6;

    const f32x4* h0v = (const f32x4*)(h0 + (size_t)b * DIM);
    const f32x4* xin = (const f32x4*)(x + (size_t)b * DIM);

    f32x4 h[4], sg[4];
#pragma unroll
    for (int v = 0; v < 4; ++v) {
        h[v] = h0v[t + v * TPB3];
        f32x4 xx = xin[t + v * TPB3];
        sg[v] = (f32x4)(1.0f) - 2.0f * xx;  // exactly +/-1
    }

    // Zx = logsumexp(sg*h*0.5)
    float lmax = -INFINITY;
#pragma unroll
    for (int v = 0; v < 4; ++v) {
        f32x4 l = sg[v] * h[v] * 0.5f;
        lmax = fmaxf(lmax, fmaxf(fmaxf(l.x, l.y), fmaxf(l.z, l.w)));
    }
    float m = block_reduce_max(lmax, redf);
    float lsum = 0.f;
#pragma unroll
    for (int v = 0; v < 4; ++v) {
        f32x4 l = sg[v] * h[v] * 0.5f;
        lsum += expf(l.x - m) + expf(l.y - m) + expf(l.z - m) + expf(l.w - m);
    }
    float S = block_reduce_sum(lsum, redf);
    float Zx = logf(S) + m;

    int rad = radius[b];
    rad = rad < 0 ? 0 : (rad > MAX_STEPS ? MAX_STEPS : rad);

    f32x4 gc[4];
    {
        const f32x4* gp = (const f32x4*)(gumbel + (size_t)b * DIM);  // step 0 row
#pragma unroll
        for (int v = 0; v < 4; ++v) gc[v] = gp[t + v * TPB3];
    }

    for (int st = 0; st < rad; ++st) {
        // scores + thread-local argmax (ascending index; strict > keeps first max)
        float best = -INFINITY; int bidx = 0;
#pragma unroll
        for (int v = 0; v < 4; ++v) {
            f32x4 l = sg[v] * h[v] * 0.5f + gc[v];
            int base = (t + v * TPB3) * 4;
            if (l.x > best) { best = l.x; bidx = base; }
            if (l.y > best) { best = l.y; bidx = base + 1; }
            if (l.z > best) { best = l.z; bidx = base + 2; }
            if (l.w > best) { best = l.w; bidx = base + 3; }
        }
        // wave reduce (min-idx tie-break)
#pragma unroll
        for (int off = 1; off < 64; off <<= 1) {
            float ov = __shfl_xor(best, off);
            int oi = __shfl_xor(bidx, off);
            if (ov > best || (ov == best && oi < bidx)) { best = ov; bidx = oi; }
        }
        if (lane == 0) { redf[wvi] = best; redi[wvi] = bidx; }
        // prefetch next gumbel row; overlaps both barriers
        if (st + 1 < rad) {
            const f32x4* gp = (const f32x4*)(gumbel + ((size_t)(st + 1) * BSIZE + b) * DIM);
#pragma unroll
            for (int v = 0; v < 4; ++v) gc[v] = gp[t + v * TPB3];
        }
        __syncthreads();  // bar1: leader entries visible
        // all threads scan the 16 leader entries (identical result)
        float bv = redf[0]; int bi = redi[0];
#pragma unroll
        for (int w = 1; w < TPB3 / 64; ++w) {
            float ov = redf[w]; int oi = redi[w];
            if (ov > bv || (ov == bv && oi < bi)) { bv = ov; bi = oi; }
        }
        const int idx = bi;
        // issue W-row loads now; latency overlaps bar2
        const f32x4* wr4 = (const f32x4*)(W + (size_t)idx * DIM);
        f32x4 wl0 = wr4[t];
        f32x4 wl1 = wr4[t + TPB3];
        f32x4 wl2 = wr4[t + 2 * TPB3];
        f32x4 wl3 = wr4[t + 3 * TPB3];
        // owner flips its sign and publishes delta = (1 - 2*x_old)
        int c4 = idx >> 2, towner = c4 & (TPB3 - 1), vsel = c4 >> 10, e = idx & 3;
        if (t == towner) {
            f32x4 s4;
            if (vsel == 0) s4 = sg[0]; else if (vsel == 1) s4 = sg[1];
            else if (vsel == 2) s4 = sg[2]; else s4 = sg[3];
            float d = (e == 0) ? s4.x : (e == 1) ? s4.y : (e == 2) ? s4.z : s4.w;
            if (e == 0) s4.x = -s4.x; else if (e == 1) s4.y = -s4.y;
            else if (e == 2) s4.z = -s4.z; else s4.w = -s4.w;
            if (vsel == 0) sg[0] = s4; else if (vsel == 1) sg[1] = s4;
            else if (vsel == 2) sg[2] = s4; else sg[3] = s4;
            s_delta = d;
        }
        __syncthreads();  // bar2: s_delta visible; also protects redf/redi reuse
        float delta = s_delta;
        h[0].x = fmaf(delta, wl0.x, h[0].x); h[0].y = fmaf(delta, wl0.y, h[0].y);
        h[0].z = fmaf(delta, wl0.z, h[0].z); h[0].w = fmaf(delta, wl0.w, h[0].w);
        h[1].x = fmaf(delta, wl1.x, h[1].x); h[1].y = fmaf(delta, wl1.y, h[1].y);
        h[1].z = fmaf(delta, wl1.z, h[1].z); h[1].w = fmaf(delta, wl1.w, h[1].w);
        h[2].x = fmaf(delta, wl2.x, h[2].x); h[2].y = fmaf(delta, wl2.y, h[2].y);
        h[2].z = fmaf(delta, wl2.z, h[2].z); h[2].w = fmaf(delta, wl2.w, h[2].w);
        h[3].x = fmaf(delta, wl3.x, h[3].x); h[3].y = fmaf(delta, wl3.y, h[3].y);
        h[3].z = fmaf(delta, wl3.z, h[3].z); h[3].w = fmaf(delta, wl3.w, h[3].w);
    }

    // Zy
    lmax = -INFINITY;
#pragma unroll
    for (int v = 0; v < 4; ++v) {
        f32x4 l = sg[v] * h[v] * 0.5f;
        lmax = fmaxf(lmax, fmaxf(fmaxf(l.x, l.y), fmaxf(l.z, l.w)));
    }
    m = block_reduce_max(lmax, redf);
    lsum = 0.f;
#pragma unroll
    for (int v = 0; v < 4; ++v) {
        f32x4 l = sg[v] * h[v] * 0.5f;
        lsum += expf(l.x - m) + expf(l.y - m) + expf(l.z - m) + expf(l.w - m);
    }
    S = block_reduce_sum(lsum, redf);
    float Zy = logf(S) + m;

    int accepted = (expf(Zx - Zy) >= au[b]) ? 1 : 0;
    f32x4* ov = (f32x4*)(out + (size_t)b * DIM);
#pragma unroll
    for (int v = 0; v < 4; ++v) {
        f32x4 y;
        y.x = (sg[v].x < 0.f) ? 1.f : 0.f;
        y.y = (sg[v].y < 0.f) ? 1.f : 0.f;
        y.z = (sg[v].z < 0.f) ? 1.f : 0.f;
        y.w = (sg[v].w < 0.f) ? 1.f : 0.f;
        ov[t + v * TPB3] = accepted ? y : xin[t + v * TPB3];
    }
}

extern "C" void kernel_launch(void* const* d_in, const int* in_sizes, int n_in,
                              void* d_out, int out_size, void* d_ws, size_t ws_size,
                              hipStream_t stream) {
    (void)in_sizes; (void)n_in; (void)out_size; (void)ws_size;
    const float* x      = (const float*)d_in[0];
    const float* W      = (const float*)d_in[1];
    const float* bias   = (const float*)d_in[2];
    const float* gumbel = (const float*)d_in[3];
    const float* au     = (const float*)d_in[4];
    const int*   radius = (const int*)d_in[5];
    float* out = (float*)d_out;

    // ws layout: xT (2 MB) | partial (NSLOTS * 2 MB = 64 MB) | h0 (2 MB)
    float* xT = (float*)d_ws;
    size_t xt_elems = (size_t)DIM * BSIZE;
    float* partial = xT + xt_elems;
    float* h0 = partial + (size_t)NSLOTS * BSIZE * DIM;

    k_xpose<<<DIM / 64, 256, 0, stream>>>(x, xT);
    dim3 g1(DIM / (TPB1 * 2), NSLOTS);  // (32, 32) = 1024 blocks
    k_matmul<<<g1, TPB1, 0, stream>>>(W, xT, partial);
    k_reduce<<<(BSIZE * DIM / 4) / 256, 256, 0, stream>>>(partial, bias, h0);
    k_sample<<<BSIZE, TPB3, 0, stream>>>(x, W, h0, gumbel, au, radius, out);
}

// Round 13
// 298.625 us; speedup vs baseline: 1.4190x; 1.1058x over previous
//
#include <hip/hip_runtime.h>
#include <cstdint>
#include <cstddef>

#define DIM 16384
#define BSIZE 32
#define MAX_STEPS 9
#define TPB1 256
#define TPB3 1024
#define JB 512
#define NSLOTS (DIM / JB)  // 32
#define BATCH 16

typedef float f32x4 __attribute__((ext_vector_type(4)));

__device__ __forceinline__ float rdlane(float v, int l) {
    return __int_as_float(__builtin_amdgcn_readlane(__float_as_int(v), l));
}

// ---------------- K0: tiled transpose x [B][D] -> xT [D][B] ----------------
__global__ __launch_bounds__(256) void k_xpose(const float* __restrict__ x,
                                               float* __restrict__ xT) {
    __shared__ float tile[64][33];
    const int j0 = blockIdx.x * 64;
    const int t = threadIdx.x;
    {
        int col = t & 63;
        int r0 = t >> 6;  // 0..3
#pragma unroll
        for (int r = 0; r < 8; ++r) {
            int row = r * 4 + r0;  // 0..31
            tile[col][row] = x[(size_t)row * DIM + j0 + col];
        }
    }
    __syncthreads();
    {
        int b = t & 31;
        int q0 = t >> 5;  // 0..7
#pragma unroll
        for (int r = 0; r < 8; ++r) {
            int jj = r * 8 + q0;  // 0..63
            xT[(size_t)(j0 + jj) * BSIZE + b] = tile[jj][b];
        }
    }
}

// ------- K1 (R9, measured best: K1 ~238us, 4.5 TB/s): probe-mirror matmul -------
// 16 W rows (f32x4/lane) issued back-to-back per batch (shape measured at
// 6.4 TB/s in the R8 pure-read probe); x rides ahead of the batch as
// 2 f32x4/lane; compile-time v_readlane extracts feed v_pk_fma_f32.
// grid (16, 32) = 512 blocks = 2/CU = 8 waves/CU.
__global__ __launch_bounds__(TPB1, 2) void k_matmul(
        const float* __restrict__ W, const float* __restrict__ xT,
        float* __restrict__ partial) {
    const int t = threadIdx.x;
    const int l = t & 63;
    const int c0 = (blockIdx.x * TPB1 + t) * 4;
    const int j0 = blockIdx.y * JB;

    f32x4 acc[BSIZE];
#pragma unroll
    for (int b = 0; b < BSIZE; ++b) acc[b] = (f32x4)(0.f);

    const float* wp = W + (size_t)j0 * DIM + c0;
    const float* xp = xT + (size_t)j0 * BSIZE;

    for (int g = 0; g < JB / BATCH; ++g) {  // 32 batches
        f32x4 xv0 = *(const f32x4*)(xp + (size_t)g * 512 + l * 4);
        f32x4 xv1 = *(const f32x4*)(xp + (size_t)g * 512 + 256 + l * 4);
        f32x4 v[BATCH];
#pragma unroll
        for (int r = 0; r < BATCH; ++r)
            v[r] = *(const f32x4*)(wp + (size_t)(g * BATCH + r) * DIM);
#pragma unroll
        for (int r = 0; r < BATCH; ++r) {
            f32x4 w4 = v[r];
#pragma unroll
            for (int b = 0; b < BSIZE; ++b) {
                float xs = (r < 8) ? rdlane(xv0[b & 3], (r & 7) * 8 + (b >> 2))
                                   : rdlane(xv1[b & 3], (r & 7) * 8 + (b >> 2));
                acc[b] = __builtin_elementwise_fma(w4, (f32x4)(xs), acc[b]);
            }
        }
    }

    float* pbase = partial + (size_t)blockIdx.y * BSIZE * DIM + c0;
#pragma unroll
    for (int b = 0; b < BSIZE; ++b)
        *(f32x4*)(pbase + (size_t)b * DIM) = acc[b];
}

// ------- K2: h0 = sum_slots partial + bias (float4, deterministic order) -------
__global__ __launch_bounds__(256) void k_reduce(const float* __restrict__ partial,
                                                const float* __restrict__ bias,
                                                float* __restrict__ h0) {
    int i4 = blockIdx.x * 256 + threadIdx.x;  // over B*DIM/4
    int c4 = i4 & (DIM / 4 - 1);
    const f32x4* p = (const f32x4*)partial;
    f32x4 s = ((const f32x4*)bias)[c4];
#pragma unroll 4
    for (int sl = 0; sl < NSLOTS; ++sl)
        s += p[(size_t)sl * (BSIZE * DIM / 4) + i4];
    ((f32x4*)h0)[i4] = s;
}

// ---------------- K3 block-wide reductions (1024 thr = 16 waves) ----------------
__device__ __forceinline__ float block_reduce_max(float v, float* red) {
#pragma unroll
    for (int off = 1; off < 64; off <<= 1) v = fmaxf(v, __shfl_xor(v, off));
    int lane = threadIdx.x & 63, wv = threadIdx.x >> 6;
    if (lane == 0) red[wv] = v;
    __syncthreads();
    float m = red[0];
#pragma unroll
    for (int w = 1; w < TPB3 / 64; ++w) m = fmaxf(m, red[w]);
    __syncthreads();  // allow red[] reuse
    return m;
}

__device__ __forceinline__ float block_reduce_sum(float v, float* red) {
#pragma unroll
    for (int off = 1; off < 64; off <<= 1) v += __shfl_xor(v, off);
    int lane = threadIdx.x & 63, wv = threadIdx.x >> 6;
    if (lane == 0) red[wv] = v;
    __syncthreads();
    float s = red[0];
#pragma unroll
    for (int w = 1; w < TPB3 / 64; ++w) s += red[w];
    __syncthreads();
    return s;
}

// ------- K3: per-row sampler, one block per batch row, h/sg in registers -------
__global__ __launch_bounds__(TPB3) void k_sample(
        const float* __restrict__ x, const float* __restrict__ W,
        const float* __restrict__ h0, const float* __restrict__ gumbel,
        const float* __restrict__ au, const int* __restrict__ radius,
        float* __restrict__ out) {
    __shared__ float redf[TPB3 / 64];
    __shared__ int   redi[TPB3 / 64];
    __shared__ float s_delta;
    const int b = blockIdx.x;
    const int t = threadIdx.x;
    const int lane = t & 63, wvi = t >> 6;

    const f32x4* h0v = (const f32x4*)(h0 + (size_t)b * DIM);
    const f32x4* xin = (const f32x4*)(x + (size_t)b * DIM);

    f32x4 h[4], sg[4];
#pragma unroll
    for (int v = 0; v < 4; ++v) {
        h[v] = h0v[t + v * TPB3];
        f32x4 xx = xin[t + v * TPB3];
        sg[v] = (f32x4)(1.0f) - 2.0f * xx;  // exactly +/-1
    }

    // Zx = logsumexp(sg*h*0.5)
    float lmax = -INFINITY;
#pragma unroll
    for (int v = 0; v < 4; ++v) {
        f32x4 l = sg[v] * h[v] * 0.5f;
        lmax = fmaxf(lmax, fmaxf(fmaxf(l.x, l.y), fmaxf(l.z, l.w)));
    }
    float m = block_reduce_max(lmax, redf);
    float lsum = 0.f;
#pragma unroll
    for (int v = 0; v < 4; ++v) {
        f32x4 l = sg[v] * h[v] * 0.5f;
        lsum += expf(l.x - m) + expf(l.y - m) + expf(l.z - m) + expf(l.w - m);
    }
    float S = block_reduce_sum(lsum, redf);
    float Zx = logf(S) + m;

    int rad = radius[b];
    rad = rad < 0 ? 0 : (rad > MAX_STEPS ? MAX_STEPS : rad);

    f32x4 gc[4];
    {
        const f32x4* gp = (const f32x4*)(gumbel + (size_t)b * DIM);  // step 0 row
#pragma unroll
        for (int v = 0; v < 4; ++v) gc[v] = gp[t + v * TPB3];
    }

    for (int st = 0; st < rad; ++st) {
        // scores + thread-local argmax (ascending index; strict > keeps first max)
        float best = -INFINITY; int bidx = 0;
#pragma unroll
        for (int v = 0; v < 4; ++v) {
            f32x4 l = sg[v] * h[v] * 0.5f + gc[v];
            int base = (t + v * TPB3) * 4;
            if (l.x > best) { best = l.x; bidx = base; }
            if (l.y > best) { best = l.y; bidx = base + 1; }
            if (l.z > best) { best = l.z; bidx = base + 2; }
            if (l.w > best) { best = l.w; bidx = base + 3; }
        }
        // wave reduce (min-idx tie-break)
#pragma unroll
        for (int off = 1; off < 64; off <<= 1) {
            float ov = __shfl_xor(best, off);
            int oi = __shfl_xor(bidx, off);
            if (ov > best || (ov == best && oi < bidx)) { best = ov; bidx = oi; }
        }
        if (lane == 0) { redf[wvi] = best; redi[wvi] = bidx; }
        // prefetch next gumbel row; overlaps both barriers
        if (st + 1 < rad) {
            const f32x4* gp = (const f32x4*)(gumbel + ((size_t)(st + 1) * BSIZE + b) * DIM);
#pragma unroll
            for (int v = 0; v < 4; ++v) gc[v] = gp[t + v * TPB3];
        }
        __syncthreads();  // bar1: leader entries visible
        // all threads scan the 16 leader entries (identical result)
        float bv = redf[0]; int bi = redi[0];
#pragma unroll
        for (int w = 1; w < TPB3 / 64; ++w) {
            float ov = redf[w]; int oi = redi[w];
            if (ov > bv || (ov == bv && oi < bi)) { bv = ov; bi = oi; }
        }
        const int idx = bi;
        // issue W-row loads now; latency overlaps bar2
        const f32x4* wr4 = (const f32x4*)(W + (size_t)idx * DIM);
        f32x4 wl0 = wr4[t];
        f32x4 wl1 = wr4[t + TPB3];
        f32x4 wl2 = wr4[t + 2 * TPB3];
        f32x4 wl3 = wr4[t + 3 * TPB3];
        // owner flips its sign and publishes delta = (1 - 2*x_old)
        int c4 = idx >> 2, towner = c4 & (TPB3 - 1), vsel = c4 >> 10, e = idx & 3;
        if (t == towner) {
            f32x4 s4;
            if (vsel == 0) s4 = sg[0]; else if (vsel == 1) s4 = sg[1];
            else if (vsel == 2) s4 = sg[2]; else s4 = sg[3];
            float d = (e == 0) ? s4.x : (e == 1) ? s4.y : (e == 2) ? s4.z : s4.w;
            if (e == 0) s4.x = -s4.x; else if (e == 1) s4.y = -s4.y;
            else if (e == 2) s4.z = -s4.z; else s4.w = -s4.w;
            if (vsel == 0) sg[0] = s4; else if (vsel == 1) sg[1] = s4;
            else if (vsel == 2) sg[2] = s4; else sg[3] = s4;
            s_delta = d;
        }
        __syncthreads();  // bar2: s_delta visible; also protects redf/redi reuse
        float delta = s_delta;
        h[0].x = fmaf(delta, wl0.x, h[0].x); h[0].y = fmaf(delta, wl0.y, h[0].y);
        h[0].z = fmaf(delta, wl0.z, h[0].z); h[0].w = fmaf(delta, wl0.w, h[0].w);
        h[1].x = fmaf(delta, wl1.x, h[1].x); h[1].y = fmaf(delta, wl1.y, h[1].y);
        h[1].z = fmaf(delta, wl1.z, h[1].z); h[1].w = fmaf(delta, wl1.w, h[1].w);
        h[2].x = fmaf(delta, wl2.x, h[2].x); h[2].y = fmaf(delta, wl2.y, h[2].y);
        h[2].z = fmaf(delta, wl2.z, h[2].z); h[2].w = fmaf(delta, wl2.w, h[2].w);
        h[3].x = fmaf(delta, wl3.x, h[3].x); h[3].y = fmaf(delta, wl3.y, h[3].y);
        h[3].z = fmaf(delta, wl3.z, h[3].z); h[3].w = fmaf(delta, wl3.w, h[3].w);
    }

    // Zy
    lmax = -INFINITY;
#pragma unroll
    for (int v = 0; v < 4; ++v) {
        f32x4 l = sg[v] * h[v] * 0.5f;
        lmax = fmaxf(lmax, fmaxf(fmaxf(l.x, l.y), fmaxf(l.z, l.w)));
    }
    m = block_reduce_max(lmax, redf);
    lsum = 0.f;
#pragma unroll
    for (int v = 0; v < 4; ++v) {
        f32x4 l = sg[v] * h[v] * 0.5f;
        lsum += expf(l.x - m) + expf(l.y - m) + expf(l.z - m) + expf(l.w - m);
    }
    S = block_reduce_sum(lsum, redf);
    float Zy = logf(S) + m;

    int accepted = (expf(Zx - Zy) >= au[b]) ? 1 : 0;
    f32x4* ov = (f32x4*)(out + (size_t)b * DIM);
#pragma unroll
    for (int v = 0; v < 4; ++v) {
        f32x4 y;
        y.x = (sg[v].x < 0.f) ? 1.f : 0.f;
        y.y = (sg[v].y < 0.f) ? 1.f : 0.f;
        y.z = (sg[v].z < 0.f) ? 1.f : 0.f;
        y.w = (sg[v].w < 0.f) ? 1.f : 0.f;
        ov[t + v * TPB3] = accepted ? y : xin[t + v * TPB3];
    }
}

extern "C" void kernel_launch(void* const* d_in, const int* in_sizes, int n_in,
                              void* d_out, int out_size, void* d_ws, size_t ws_size,
                              hipStream_t stream) {
    (void)in_sizes; (void)n_in; (void)out_size; (void)ws_size;
    const float* x      = (const float*)d_in[0];
    const float* W      = (const float*)d_in[1];
    const float* bias   = (const float*)d_in[2];
    const float* gumbel = (const float*)d_in[3];
    const float* au     = (const float*)d_in[4];
    const int*   radius = (const int*)d_in[5];
    float* out = (float*)d_out;

    // ws layout: xT (2 MB) | partial (NSLOTS * 2 MB = 64 MB) | h0 (2 MB)
    float* xT = (float*)d_ws;
    size_t xt_elems = (size_t)DIM * BSIZE;
    float* partial = xT + xt_elems;
    float* h0 = partial + (size_t)NSLOTS * BSIZE * DIM;

    k_xpose<<<DIM / 64, 256, 0, stream>>>(x, xT);
    dim3 g1(DIM / (TPB1 * 4), NSLOTS);  // (16, 32) = 512 blocks
    k_matmul<<<g1, TPB1, 0, stream>>>(W, xT, partial);
    k_reduce<<<(BSIZE * DIM / 4) / 256, 256, 0, stream>>>(partial, bias, h0);
    k_sample<<<BSIZE, TPB3, 0, stream>>>(x, W, h0, gumbel, au, radius, out);
}